// Round 2
// baseline (476.382 us; speedup 1.0000x reference)
//
#include <hip/hip_runtime.h>
#include <hip/hip_bf16.h>

// Problem constants
#define NB 16      // batch
#define NN 1024    // nodes
#define CIN 16
#define TT 36
#define KK 3
#define COUT 64
#define CT 576     // CIN*TT
#define KB 48      // KK*NB

typedef __attribute__((ext_vector_type(8))) short bf16x8;
typedef __attribute__((ext_vector_type(4))) float f32x4;

__device__ __forceinline__ unsigned short f2bf(float f) {
    union { float f; unsigned int u; } v; v.f = f;
    unsigned int r = v.u + 0x7FFF + ((v.u >> 16) & 1);
    return (unsigned short)(r >> 16);
}
__device__ __forceinline__ float bf2f(unsigned int lo16) {
    union { unsigned int u; float f; } v; v.u = lo16 << 16; return v.f;
}

// -------- prep_a: At[l][n][m] = bf16(cheb[k0+(l>>4)][m][n] * SAt[l&15][m][n]) --------
// grid(256, nkb), 256 threads. 64x64 tile transpose via LDS.
__global__ __launch_bounds__(256) void prep_a(const float* __restrict__ cheb,
                                              const float* __restrict__ sat,
                                              ushort* __restrict__ At, int k0) {
    __shared__ ushort tile[64][68];
    const int l = blockIdx.y;
    const int k = k0 + (l >> 4), b = l & 15;
    const int n0 = (blockIdx.x & 15) * 64;
    const int m0 = (blockIdx.x >> 4) * 64;
    const int tid = threadIdx.x;
    const float* cb = cheb + (size_t)k * NN * NN;
    const float* sa = sat + (size_t)b * NN * NN;
#pragma unroll
    for (int i = 0; i < 4; ++i) {
        int f = i * 256 + tid;
        int mr = f >> 4, c4 = (f & 15) << 2;
        size_t g = (size_t)(m0 + mr) * NN + n0 + c4;
        float4 cv = *(const float4*)(cb + g);
        float4 sv = *(const float4*)(sa + g);
        ushort4 u;
        u.x = f2bf(cv.x * sv.x); u.y = f2bf(cv.y * sv.y);
        u.z = f2bf(cv.z * sv.z); u.w = f2bf(cv.w * sv.w);
        *(ushort4*)&tile[mr][c4] = u;
    }
    __syncthreads();
    ushort* outp = At + (size_t)l * NN * NN;
#pragma unroll
    for (int i = 0; i < 4; ++i) {
        int f = i * 256 + tid;
        int n = f >> 4, m4 = (f & 15) << 2;
        ushort4 u;
        u.x = tile[m4 + 0][n]; u.y = tile[m4 + 1][n];
        u.z = tile[m4 + 2][n]; u.w = tile[m4 + 3][n];
        *(ushort4*)(outp + (size_t)(n0 + n) * NN + m0 + m4) = u;
    }
}

// -------- prep_x: Xt[b][ct][m] = bf16(x[b][m][ct]) --------
__global__ __launch_bounds__(256) void prep_x(const float* __restrict__ x,
                                              ushort* __restrict__ Xt) {
    __shared__ ushort tile[64][68];
    const int b = blockIdx.y;
    const int m0 = (blockIdx.x & 15) * 64;
    const int c0 = (blockIdx.x >> 4) * 64;
    const int tid = threadIdx.x;
    const float* xb = x + (size_t)b * NN * CT;
#pragma unroll
    for (int i = 0; i < 4; ++i) {
        int f = i * 256 + tid;
        int mr = f >> 4, c4 = (f & 15) << 2;
        float4 v = *(const float4*)(xb + (size_t)(m0 + mr) * CT + c0 + c4);
        ushort4 u;
        u.x = f2bf(v.x); u.y = f2bf(v.y); u.z = f2bf(v.z); u.w = f2bf(v.w);
        *(ushort4*)&tile[mr][c4] = u;
    }
    __syncthreads();
    ushort* outp = Xt + (size_t)b * CT * NN;
#pragma unroll
    for (int i = 0; i < 4; ++i) {
        int f = i * 256 + tid;
        int n = f >> 4, m4 = (f & 15) << 2;
        ushort4 u;
        u.x = tile[m4 + 0][n]; u.y = tile[m4 + 1][n];
        u.z = tile[m4 + 2][n]; u.w = tile[m4 + 3][n];
        *(ushort4*)(outp + (size_t)(c0 + n) * NN + m0 + m4) = u;
    }
}

// -------- gemm1: rhs[l][n][ct] = sum_m At[l][n][m] * Xt[l&15][ct][m] --------
// Tile BM=128(n) x BN=192(ct) x BK=64. grid(24, nkb), 256 threads (4 waves 2x2).
__global__ __launch_bounds__(256) void gemm1(const ushort* __restrict__ At,
                                             const ushort* __restrict__ Xt,
                                             ushort* __restrict__ rhs) {
    __shared__ ushort lA[128 * 64];
    __shared__ ushort lB[192 * 64];
    const int tid = threadIdx.x;
    const int l = blockIdx.y;
    const int b = l & 15;
    const int nt = blockIdx.x / 3, ctt = blockIdx.x % 3;
    const int n0 = nt * 128, ct0 = ctt * 192;
    const ushort* Ab = At + (size_t)l * NN * NN + (size_t)n0 * NN;
    const ushort* Bb = Xt + (size_t)b * CT * NN + (size_t)ct0 * NN;
    const int w = tid >> 6, lane = tid & 63;
    const int wr = w >> 1, wc = w & 1;
    const int lrow = lane & 15, quad = lane >> 4;
    f32x4 acc[4][6] = {};

    for (int kt = 0; kt < 16; ++kt) {
        const int mk = kt * 64;
#pragma unroll
        for (int i = 0; i < 4; ++i) {
            int f = i * 256 + tid;
            int row = f >> 3, kk = (f & 7) << 3;
            __builtin_amdgcn_global_load_lds(
                (const __attribute__((address_space(1))) void*)(Ab + (size_t)row * NN + mk + kk),
                (__attribute__((address_space(3))) void*)(&lA[f * 8]), 16, 0, 0);
        }
#pragma unroll
        for (int i = 0; i < 6; ++i) {
            int f = i * 256 + tid;
            int row = f >> 3, kk = (f & 7) << 3;
            __builtin_amdgcn_global_load_lds(
                (const __attribute__((address_space(1))) void*)(Bb + (size_t)row * NN + mk + kk),
                (__attribute__((address_space(3))) void*)(&lB[f * 8]), 16, 0, 0);
        }
        __syncthreads();
#pragma unroll
        for (int k0 = 0; k0 < 64; k0 += 32) {
            bf16x8 af[4], bfr[6];
#pragma unroll
            for (int mi = 0; mi < 4; ++mi)
                af[mi] = *(const bf16x8*)&lA[(wr * 64 + mi * 16 + lrow) * 64 + k0 + quad * 8];
#pragma unroll
            for (int ni = 0; ni < 6; ++ni)
                bfr[ni] = *(const bf16x8*)&lB[(wc * 96 + ni * 16 + lrow) * 64 + k0 + quad * 8];
#pragma unroll
            for (int mi = 0; mi < 4; ++mi)
#pragma unroll
                for (int ni = 0; ni < 6; ++ni)
                    acc[mi][ni] = __builtin_amdgcn_mfma_f32_16x16x32_bf16(
                        af[mi], bfr[ni], acc[mi][ni], 0, 0, 0);
        }
        __syncthreads();
    }

    // epilogue: C/D layout col = lane&15, row = quad*4 + reg (m89-verified)
    ushort* outp = rhs + (size_t)l * NN * CT;
#pragma unroll
    for (int mi = 0; mi < 4; ++mi)
#pragma unroll
        for (int ni = 0; ni < 6; ++ni)
#pragma unroll
            for (int r = 0; r < 4; ++r) {
                int row = n0 + wr * 64 + mi * 16 + quad * 4 + r;
                int col = ct0 + wc * 96 + ni * 16 + lrow;
                outp[(size_t)row * CT + col] = f2bf(acc[mi][ni][r]);
            }
}

// -------- apply_theta: out[b,n,o,t] (+)= sum over nk k's of rhs*theta, opt relu --------
// rhs layout: [lk*16 + b][n][ct], theta indexed from global k0+lk. grid(NN, NB).
__global__ __launch_bounds__(256) void apply_theta(const ushort* __restrict__ rhs,
                                                   const float* __restrict__ theta,
                                                   float* __restrict__ out,
                                                   int k0, int nk, int first, int do_relu) {
    __shared__ float rs[48 * 48];      // [lkc][tg(4)*12]
    __shared__ float th_s[48 * 64];    // [lkc][o]
    __shared__ float outst[COUT * TT];
    const int tid = threadIdx.x;
    const int n = blockIdx.x, b = blockIdx.y;

    for (int f = tid; f < nk * 256; f += 256)
        *(float4*)&th_s[f * 4] = *(const float4*)&theta[(size_t)k0 * 1024 + f * 4];

    for (int u = tid; u < nk * 288; u += 256) {
        int lkc = u / 18, r = u % 18;          // 18 ushort2 per (lk,c)
        int lk = lkc >> 4, c = lkc & 15;
        size_t g = ((size_t)(lk * NB + b) * NN + n) * CT + c * TT + r * 2;
        unsigned int v = *(const unsigned int*)(rhs + g);
        int t0 = r * 2, t1 = t0 + 1;
        rs[lkc * 48 + (t0 / 9) * 12 + (t0 % 9)] = bf2f(v & 0xffffu);
        rs[lkc * 48 + (t1 / 9) * 12 + (t1 % 9)] = bf2f(v >> 16);
    }
    __syncthreads();

    const int o = tid >> 2, tg = tid & 3;
    float acc[9] = {};
    for (int lkc = 0; lkc < nk * 16; ++lkc) {
        float th = th_s[lkc * 64 + o];
        const float* rp = &rs[lkc * 48 + tg * 12];
        float4 a = *(const float4*)(rp);
        float4 bb = *(const float4*)(rp + 4);
        float cc = rp[8];
        acc[0] += th * a.x;  acc[1] += th * a.y;  acc[2] += th * a.z;  acc[3] += th * a.w;
        acc[4] += th * bb.x; acc[5] += th * bb.y; acc[6] += th * bb.z; acc[7] += th * bb.w;
        acc[8] += th * cc;
    }
#pragma unroll
    for (int j = 0; j < 9; ++j)
        outst[o * TT + tg * 9 + j] = acc[j];
    __syncthreads();

    float* ob = out + ((size_t)b * NN + n) * (COUT * TT);
    for (int f = tid; f < 576; f += 256) {
        float4 v = *(const float4*)&outst[f * 4];
        if (!first) {
            float4 p = *(const float4*)&ob[f * 4];
            v.x += p.x; v.y += p.y; v.z += p.z; v.w += p.w;
        }
        if (do_relu) {
            v.x = fmaxf(v.x, 0.f); v.y = fmaxf(v.y, 0.f);
            v.z = fmaxf(v.z, 0.f); v.w = fmaxf(v.w, 0.f);
        }
        *(float4*)&ob[f * 4] = v;
    }
}

// -------- naive fallback: zero workspace, fully fused --------
__global__ __launch_bounds__(256) void naive_fused(const float* __restrict__ x,
                                                   const float* __restrict__ sat,
                                                   const float* __restrict__ cheb,
                                                   const float* __restrict__ theta,
                                                   float* __restrict__ out) {
    __shared__ float w[3][1024];
    __shared__ float rs[3][576];
    const int tid = threadIdx.x;
    const int n = blockIdx.x, b = blockIdx.y;
    for (int f = tid; f < 3 * 1024; f += 256) {
        int k = f >> 10, m = f & 1023;
        w[k][m] = cheb[(size_t)k * NN * NN + (size_t)m * NN + n] *
                  sat[(size_t)b * NN * NN + (size_t)m * NN + n];
    }
    __syncthreads();
    float a0[3] = {}, a1[3] = {}, a2[3] = {};
    const float* xb = x + (size_t)b * NN * CT;
    for (int m = 0; m < 1024; ++m) {
        const float* xr = xb + (size_t)m * CT;
        float x0 = xr[tid];
        float x1 = xr[256 + tid];
        float x2 = (tid < 64) ? xr[512 + tid] : 0.f;
#pragma unroll
        for (int k = 0; k < 3; ++k) {
            float wm = w[k][m];
            a0[k] += wm * x0; a1[k] += wm * x1; a2[k] += wm * x2;
        }
    }
#pragma unroll
    for (int k = 0; k < 3; ++k) {
        rs[k][tid] = a0[k];
        rs[k][256 + tid] = a1[k];
        if (tid < 64) rs[k][512 + tid] = a2[k];
    }
    __syncthreads();
    const int o = tid >> 2, tg = tid & 3;
    float oa[9] = {};
    for (int kc = 0; kc < 48; ++kc) {
        int k = kc >> 4, c = kc & 15;
        float th = theta[kc * 64 + o];
        const float* rp = &rs[k][c * TT + tg * 9];
#pragma unroll
        for (int j = 0; j < 9; ++j) oa[j] += th * rp[j];
    }
    float* ob = out + ((size_t)b * NN + n) * (COUT * TT);
#pragma unroll
    for (int j = 0; j < 9; ++j)
        ob[o * TT + tg * 9 + j] = fmaxf(oa[j], 0.f);
}

extern "C" void kernel_launch(void* const* d_in, const int* in_sizes, int n_in,
                              void* d_out, int out_size, void* d_ws, size_t ws_size,
                              hipStream_t stream) {
    const float* x     = (const float*)d_in[0];   // [B,N,CIN,T]
    const float* sat   = (const float*)d_in[1];   // [B,N,N]
    const float* cheb  = (const float*)d_in[2];   // [K,N,N]
    const float* theta = (const float*)d_in[3];   // [K,CIN,COUT]
    float* out = (float*)d_out;

    const size_t XT   = (size_t)NB * CT * NN;     // ushorts: 9.4M  (18.9 MB)
    const size_t RHSK = (size_t)16 * NN * CT;     // ushorts per k  (18.9 MB)
    const size_t ATK  = (size_t)16 * NN * NN;     // ushorts per k  (33.6 MB)
    const size_t needB = (XT + 3 * RHSK + ATK) * 2;  // 109,051,904 B
    const size_t needC = (XT + RHSK + ATK) * 2;      //  71,303,168 B

    ushort* Xt = (ushort*)d_ws;
    if (ws_size >= needB) {
        ushort* rhs = Xt + XT;
        ushort* At  = rhs + 3 * RHSK;
        prep_x<<<dim3(144, NB), 256, 0, stream>>>(x, Xt);
        for (int k = 0; k < 3; ++k) {
            prep_a<<<dim3(256, 16), 256, 0, stream>>>(cheb, sat, At, k);
            gemm1<<<dim3(24, 16), 256, 0, stream>>>(At, Xt, rhs + (size_t)k * RHSK);
        }
        apply_theta<<<dim3(NN, NB), 256, 0, stream>>>(rhs, theta, out, 0, 3, 1, 1);
    } else if (ws_size >= needC) {
        ushort* rhs = Xt + XT;
        ushort* At  = rhs + RHSK;
        prep_x<<<dim3(144, NB), 256, 0, stream>>>(x, Xt);
        for (int k = 0; k < 3; ++k) {
            prep_a<<<dim3(256, 16), 256, 0, stream>>>(cheb, sat, At, k);
            gemm1<<<dim3(24, 16), 256, 0, stream>>>(At, Xt, rhs);
            apply_theta<<<dim3(NN, NB), 256, 0, stream>>>(rhs, theta, out,
                                                          k, 1, k == 0, k == 2);
        }
    } else {
        naive_fused<<<dim3(NN, NB), 256, 0, stream>>>(x, sat, cheb, theta, out);
    }
}

// Round 3
// 464.907 us; speedup vs baseline: 1.0247x; 1.0247x over previous
//
#include <hip/hip_runtime.h>
#include <hip/hip_bf16.h>

// Problem constants
#define NB 16      // batch
#define NN 1024    // nodes
#define CIN 16
#define TT 36
#define KK 3
#define COUT 64
#define CT 576     // CIN*TT
#define KB 48      // KK*NB

typedef __attribute__((ext_vector_type(8))) short bf16x8;
typedef __attribute__((ext_vector_type(4))) float f32x4;

__device__ __forceinline__ unsigned short f2bf(float f) {
    union { float f; unsigned int u; } v; v.f = f;
    unsigned int r = v.u + 0x7FFF + ((v.u >> 16) & 1);
    return (unsigned short)(r >> 16);
}
__device__ __forceinline__ float bf2f(unsigned int lo16) {
    union { unsigned int u; float f; } v; v.u = lo16 << 16; return v.f;
}

// -------- prep_a: At[l_loc][n - n_base][m] = bf16(cheb[k][m][n] * SAt[b][m][n]) --------
// gl = k0*16 + blockIdx.y; k = gl>>4, b = gl&15. grid(ntiles*16, nl).
__global__ __launch_bounds__(256) void prep_a(const float* __restrict__ cheb,
                                              const float* __restrict__ sat,
                                              ushort* __restrict__ At,
                                              int k0, int n_base, int rows) {
    __shared__ ushort tile[64][68];
    const int ntiles = rows >> 6;
    const int gl = k0 * 16 + blockIdx.y;
    const int k = gl >> 4, b = gl & 15;
    const int n0 = n_base + (blockIdx.x % ntiles) * 64;
    const int m0 = (blockIdx.x / ntiles) * 64;
    const int tid = threadIdx.x;
    const float* cb = cheb + (size_t)k * NN * NN;
    const float* sa = sat + (size_t)b * NN * NN;
#pragma unroll
    for (int i = 0; i < 4; ++i) {
        int f = i * 256 + tid;
        int mr = f >> 4, c4 = (f & 15) << 2;
        size_t g = (size_t)(m0 + mr) * NN + n0 + c4;
        float4 cv = *(const float4*)(cb + g);
        float4 sv = *(const float4*)(sa + g);
        ushort4 u;
        u.x = f2bf(cv.x * sv.x); u.y = f2bf(cv.y * sv.y);
        u.z = f2bf(cv.z * sv.z); u.w = f2bf(cv.w * sv.w);
        *(ushort4*)&tile[mr][c4] = u;
    }
    __syncthreads();
    ushort* outp = At + (size_t)blockIdx.y * rows * NN;
#pragma unroll
    for (int i = 0; i < 4; ++i) {
        int f = i * 256 + tid;
        int n = f >> 4, m4 = (f & 15) << 2;
        ushort4 u;
        u.x = tile[m4 + 0][n]; u.y = tile[m4 + 1][n];
        u.z = tile[m4 + 2][n]; u.w = tile[m4 + 3][n];
        *(ushort4*)(outp + (size_t)(n0 - n_base + n) * NN + m0 + m4) = u;
    }
}

// -------- prep_x: Xt[b][ct'][m] = bf16(x[b][m][c][t]), ct' = t*16 + c --------
__global__ __launch_bounds__(256) void prep_x(const float* __restrict__ x,
                                              ushort* __restrict__ Xt) {
    __shared__ ushort tile[64][68];
    const int b = blockIdx.y;
    const int m0 = (blockIdx.x & 15) * 64;
    const int c0 = (blockIdx.x >> 4) * 64;   // linear ct = c*36+t tile base
    const int tid = threadIdx.x;
    const float* xb = x + (size_t)b * NN * CT;
#pragma unroll
    for (int i = 0; i < 4; ++i) {
        int f = i * 256 + tid;
        int mr = f >> 4, c4 = (f & 15) << 2;
        float4 v = *(const float4*)(xb + (size_t)(m0 + mr) * CT + c0 + c4);
        ushort4 u;
        u.x = f2bf(v.x); u.y = f2bf(v.y); u.z = f2bf(v.z); u.w = f2bf(v.w);
        *(ushort4*)&tile[mr][c4] = u;
    }
    __syncthreads();
    ushort* outp = Xt + (size_t)b * CT * NN;
#pragma unroll
    for (int i = 0; i < 4; ++i) {
        int f = i * 256 + tid;
        int n = f >> 4, m4 = (f & 15) << 2;
        int ctlin = c0 + n;                     // = c*36 + t
        int c = ctlin / 36, t = ctlin - 36 * c;
        int ctp = t * 16 + c;                   // t-major permuted row
        ushort4 u;
        u.x = tile[m4 + 0][n]; u.y = tile[m4 + 1][n];
        u.z = tile[m4 + 2][n]; u.w = tile[m4 + 3][n];
        *(ushort4*)(outp + (size_t)ctp * NN + m0 + m4) = u;
    }
}

// -------- gemm1: rhs2[b][n][t][k*16+c] = sum_m At[n][m] * Xt[b][ct'][m] --------
// Tile BM=128(n) x BN=192(ct') x BK=64. Epilogue LDS-staged -> 32B segments.
__global__ __launch_bounds__(256) void gemm1(const ushort* __restrict__ At,
                                             const ushort* __restrict__ Xt,
                                             ushort* __restrict__ rhs2,
                                             int k0, int n_base, int rows) {
    __shared__ ushort smem[128 * 200];            // 51200 ushorts? no: 25600
    // note: 128*200 = 25600 elems = 51.2 KB; lA/lB use first 20480 elems.
    ushort* lA = smem;                            // 128*64
    ushort* lB = smem + 128 * 64;                 // 192*64
    const int tid = threadIdx.x;
    const int gl = k0 * 16 + blockIdx.y;
    const int b = gl & 15, k = gl >> 4;
    const int nt = blockIdx.x / 3, ctt = blockIdx.x % 3;
    const int nloc0 = nt * 128;
    const int ct0 = ctt * 192;
    const ushort* Ab = At + (size_t)blockIdx.y * rows * NN + (size_t)nloc0 * NN;
    const ushort* Bb = Xt + (size_t)b * CT * NN + (size_t)ct0 * NN;
    const int w = tid >> 6, lane = tid & 63;
    const int wr = w >> 1, wc = w & 1;
    const int lrow = lane & 15, quad = lane >> 4;
    f32x4 acc[4][6] = {};

    for (int kt = 0; kt < 16; ++kt) {
        const int mk = kt * 64;
#pragma unroll
        for (int i = 0; i < 4; ++i) {
            int f = i * 256 + tid;
            int row = f >> 3, kk = (f & 7) << 3;
            __builtin_amdgcn_global_load_lds(
                (const __attribute__((address_space(1))) void*)(Ab + (size_t)row * NN + mk + kk),
                (__attribute__((address_space(3))) void*)(&lA[f * 8]), 16, 0, 0);
        }
#pragma unroll
        for (int i = 0; i < 6; ++i) {
            int f = i * 256 + tid;
            int row = f >> 3, kk = (f & 7) << 3;
            __builtin_amdgcn_global_load_lds(
                (const __attribute__((address_space(1))) void*)(Bb + (size_t)row * NN + mk + kk),
                (__attribute__((address_space(3))) void*)(&lB[f * 8]), 16, 0, 0);
        }
        __syncthreads();
#pragma unroll
        for (int kk0 = 0; kk0 < 64; kk0 += 32) {
            bf16x8 af[4], bfr[6];
#pragma unroll
            for (int mi = 0; mi < 4; ++mi)
                af[mi] = *(const bf16x8*)&lA[(wr * 64 + mi * 16 + lrow) * 64 + kk0 + quad * 8];
#pragma unroll
            for (int ni = 0; ni < 6; ++ni)
                bfr[ni] = *(const bf16x8*)&lB[(wc * 96 + ni * 16 + lrow) * 64 + kk0 + quad * 8];
#pragma unroll
            for (int mi = 0; mi < 4; ++mi)
#pragma unroll
                for (int ni = 0; ni < 6; ++ni)
                    acc[mi][ni] = __builtin_amdgcn_mfma_f32_16x16x32_bf16(
                        af[mi], bfr[ni], acc[mi][ni], 0, 0, 0);
        }
        __syncthreads();
    }

    // stage C (bf16) into LDS: row stride 200 breaks bank alignment
#pragma unroll
    for (int mi = 0; mi < 4; ++mi)
#pragma unroll
        for (int ni = 0; ni < 6; ++ni)
#pragma unroll
            for (int r = 0; r < 4; ++r)
                smem[(wr * 64 + mi * 16 + quad * 4 + r) * 200 + wc * 96 + ni * 16 + lrow] =
                    f2bf(acc[mi][ni][r]);
    __syncthreads();

    // cooperative store: 128 n x 12 t x 32B (16 c) segments into rhs2[b][n][t][48]
    for (int f = tid; f < 1536; f += 256) {
        int n = f / 12, tl = f - 12 * (f / 12);
        int t = ctt * 12 + tl;
        uint4 v0 = *(const uint4*)&smem[n * 200 + tl * 16];
        uint4 v1 = *(const uint4*)&smem[n * 200 + tl * 16 + 8];
        size_t g = (((size_t)b * NN + n_base + nloc0 + n) * 36 + t) * 48 + k * 16;
        *(uint4*)(rhs2 + g) = v0;
        *(uint4*)(rhs2 + g + 8) = v1;
    }
}

// -------- apply_mfma: out[b,n,o,t] = relu(sum_kc rhs2[b,n,t,kc] * theta[kc,o]) --------
// GEMM per (b,n): C[o=64][t=36] = thT[64][K=48pad64] x rhs2row^T. Wave per (b,n).
__global__ __launch_bounds__(256) void apply_mfma(const ushort* __restrict__ rhs2,
                                                  const float* __restrict__ theta,
                                                  float* __restrict__ out) {
    __shared__ ushort thT[64 * 72];   // [o][kc], rows kc in [48,64) zeroed
    const int tid = threadIdx.x;
    for (int f = tid; f < 64 * 64; f += 256) {
        int o = f >> 6, kc = f & 63;
        float v = (kc < 48) ? theta[kc * 64 + o] : 0.f;
        thT[o * 72 + kc] = f2bf(v);
    }
    __syncthreads();
    const int w = tid >> 6, lane = tid & 63;
    const int bn = blockIdx.x * 4 + w;            // b*1024 + n
    const ushort* rrow = rhs2 + (size_t)bn * (36 * 48);
    const int lrow = lane & 15, quad = lane >> 4;

    bf16x8 a[4][2];
#pragma unroll
    for (int mi = 0; mi < 4; ++mi)
#pragma unroll
        for (int kc = 0; kc < 2; ++kc)
            a[mi][kc] = *(const bf16x8*)&thT[(mi * 16 + lrow) * 72 + kc * 32 + quad * 8];

    f32x4 acc[4][3] = {};
#pragma unroll
    for (int ni = 0; ni < 3; ++ni)
#pragma unroll
        for (int kc = 0; kc < 2; ++kc) {
            // col (t) = ni*16 + lrow; cols >= 36 & kc-pad read in-bounds garbage,
            // masked by zero theta rows / discarded at store.
            bf16x8 bf = *(const bf16x8*)(rrow + (ni * 16 + lrow) * 48 + kc * 32 + quad * 8);
#pragma unroll
            for (int mi = 0; mi < 4; ++mi)
                acc[mi][ni] = __builtin_amdgcn_mfma_f32_16x16x32_bf16(
                    a[mi][kc], bf, acc[mi][ni], 0, 0, 0);
        }

    float* ob = out + (size_t)bn * (COUT * TT);
#pragma unroll
    for (int mi = 0; mi < 4; ++mi)
#pragma unroll
        for (int ni = 0; ni < 3; ++ni)
#pragma unroll
            for (int r = 0; r < 4; ++r) {
                int o = mi * 16 + quad * 4 + r;
                int t = ni * 16 + lrow;
                if (t < 36) ob[o * TT + t] = fmaxf(acc[mi][ni][r], 0.f);
            }
}

// -------- naive fallback: zero workspace, fully fused --------
__global__ __launch_bounds__(256) void naive_fused(const float* __restrict__ x,
                                                   const float* __restrict__ sat,
                                                   const float* __restrict__ cheb,
                                                   const float* __restrict__ theta,
                                                   float* __restrict__ out) {
    __shared__ float wgt[3][1024];
    __shared__ float rs[3][576];
    const int tid = threadIdx.x;
    const int n = blockIdx.x, b = blockIdx.y;
    for (int f = tid; f < 3 * 1024; f += 256) {
        int k = f >> 10, m = f & 1023;
        wgt[k][m] = cheb[(size_t)k * NN * NN + (size_t)m * NN + n] *
                    sat[(size_t)b * NN * NN + (size_t)m * NN + n];
    }
    __syncthreads();
    float a0[3] = {}, a1[3] = {}, a2[3] = {};
    const float* xb = x + (size_t)b * NN * CT;
    for (int m = 0; m < 1024; ++m) {
        const float* xr = xb + (size_t)m * CT;
        float x0 = xr[tid];
        float x1 = xr[256 + tid];
        float x2 = (tid < 64) ? xr[512 + tid] : 0.f;
#pragma unroll
        for (int k = 0; k < 3; ++k) {
            float wm = wgt[k][m];
            a0[k] += wm * x0; a1[k] += wm * x1; a2[k] += wm * x2;
        }
    }
#pragma unroll
    for (int k = 0; k < 3; ++k) {
        rs[k][tid] = a0[k];
        rs[k][256 + tid] = a1[k];
        if (tid < 64) rs[k][512 + tid] = a2[k];
    }
    __syncthreads();
    const int o = tid >> 2, tg = tid & 3;
    float oa[9] = {};
    for (int kc = 0; kc < 48; ++kc) {
        int k = kc >> 4, c = kc & 15;
        float th = theta[kc * 64 + o];
        const float* rp = &rs[k][c * TT + tg * 9];
#pragma unroll
        for (int j = 0; j < 9; ++j) oa[j] += th * rp[j];
    }
    float* ob = out + ((size_t)b * NN + n) * (COUT * TT);
#pragma unroll
    for (int j = 0; j < 9; ++j)
        ob[o * TT + tg * 9 + j] = fmaxf(oa[j], 0.f);
}

extern "C" void kernel_launch(void* const* d_in, const int* in_sizes, int n_in,
                              void* d_out, int out_size, void* d_ws, size_t ws_size,
                              hipStream_t stream) {
    const float* x     = (const float*)d_in[0];   // [B,N,CIN,T]
    const float* sat   = (const float*)d_in[1];   // [B,N,N]
    const float* cheb  = (const float*)d_in[2];   // [K,N,N]
    const float* theta = (const float*)d_in[3];   // [K,CIN,COUT]
    float* out = (float*)d_out;

    const size_t RHS2 = (size_t)NB * NN * 36 * 48;   // 28.3M ushorts (56.6 MB)
    const size_t XT   = (size_t)NB * CT * NN;        //  9.4M (18.9 MB)
    const size_t ATK  = (size_t)16 * NN * NN;        // 16.8M (33.6 MB) per-k chunk
    const size_t ATNS = (size_t)KB * 512 * NN;       // 25.2M (50.3 MB) n-half chunk
    const size_t needSplit = (RHS2 + XT + ATNS) * 2; // 125,829,120 B
    const size_t needB     = (RHS2 + XT + ATK) * 2;  // 109,051,904 B

    // layout: rhs2 FIRST (apply's bounded over-reads land in Xt), then Xt, At
    ushort* rhs2 = (ushort*)d_ws;
    ushort* Xt   = rhs2 + RHS2;
    ushort* At   = Xt + XT;

    if (ws_size >= needSplit) {
        prep_x<<<dim3(144, NB), 256, 0, stream>>>(x, Xt);
        for (int half = 0; half < 2; ++half) {
            int nb = half * 512;
            prep_a<<<dim3(128, KB), 256, 0, stream>>>(cheb, sat, At, 0, nb, 512);
            gemm1<<<dim3(12, KB), 256, 0, stream>>>(At, Xt, rhs2, 0, nb, 512);
        }
        apply_mfma<<<dim3(NB * NN / 4), 256, 0, stream>>>(rhs2, theta, out);
    } else if (ws_size >= needB) {
        prep_x<<<dim3(144, NB), 256, 0, stream>>>(x, Xt);
        for (int k = 0; k < 3; ++k) {
            prep_a<<<dim3(256, 16), 256, 0, stream>>>(cheb, sat, At, k, 0, 1024);
            gemm1<<<dim3(24, 16), 256, 0, stream>>>(At, Xt, rhs2, k, 0, 1024);
        }
        apply_mfma<<<dim3(NB * NN / 4), 256, 0, stream>>>(rhs2, theta, out);
    } else {
        naive_fused<<<dim3(NN, NB), 256, 0, stream>>>(x, sat, cheb, theta, out);
    }
}

// Round 4
// 445.142 us; speedup vs baseline: 1.0702x; 1.0444x over previous
//
#include <hip/hip_runtime.h>
#include <hip/hip_bf16.h>

// Problem constants
#define NB 16      // batch
#define NN 1024    // nodes
#define CIN 16
#define TT 36
#define KK 3
#define COUT 64
#define CT 576     // CIN*TT
#define KB 48      // KK*NB

typedef __attribute__((ext_vector_type(8))) short bf16x8;
typedef __attribute__((ext_vector_type(4))) float f32x4;

__device__ __forceinline__ unsigned short f2bf(float f) {
    union { float f; unsigned int u; } v; v.f = f;
    unsigned int r = v.u + 0x7FFF + ((v.u >> 16) & 1);
    return (unsigned short)(r >> 16);
}

// -------- prep_a: At[l_loc][n - n_base][m] = bf16(cheb[k][m][n] * SAt[b][m][n]) --------
__global__ __launch_bounds__(256) void prep_a(const float* __restrict__ cheb,
                                              const float* __restrict__ sat,
                                              ushort* __restrict__ At,
                                              int k0, int n_base, int rows) {
    __shared__ ushort tile[64][68];
    const int ntiles = rows >> 6;
    const int gl = k0 * 16 + blockIdx.y;
    const int k = gl >> 4, b = gl & 15;
    const int n0 = n_base + (blockIdx.x % ntiles) * 64;
    const int m0 = (blockIdx.x / ntiles) * 64;
    const int tid = threadIdx.x;
    const float* cb = cheb + (size_t)k * NN * NN;
    const float* sa = sat + (size_t)b * NN * NN;
#pragma unroll
    for (int i = 0; i < 4; ++i) {
        int f = i * 256 + tid;
        int mr = f >> 4, c4 = (f & 15) << 2;
        size_t g = (size_t)(m0 + mr) * NN + n0 + c4;
        float4 cv = *(const float4*)(cb + g);
        float4 sv = *(const float4*)(sa + g);
        ushort4 u;
        u.x = f2bf(cv.x * sv.x); u.y = f2bf(cv.y * sv.y);
        u.z = f2bf(cv.z * sv.z); u.w = f2bf(cv.w * sv.w);
        *(ushort4*)&tile[mr][c4] = u;
    }
    __syncthreads();
    ushort* outp = At + (size_t)blockIdx.y * rows * NN;
#pragma unroll
    for (int i = 0; i < 4; ++i) {
        int f = i * 256 + tid;
        int n = f >> 4, m4 = (f & 15) << 2;
        ushort4 u;
        u.x = tile[m4 + 0][n]; u.y = tile[m4 + 1][n];
        u.z = tile[m4 + 2][n]; u.w = tile[m4 + 3][n];
        *(ushort4*)(outp + (size_t)(n0 - n_base + n) * NN + m0 + m4) = u;
    }
}

// -------- prep_x: Xt[b][ct'][m] = bf16(x[b][m][c][t]), ct' = t*16 + c --------
__global__ __launch_bounds__(256) void prep_x(const float* __restrict__ x,
                                              ushort* __restrict__ Xt) {
    __shared__ ushort tile[64][68];
    const int b = blockIdx.y;
    const int m0 = (blockIdx.x & 15) * 64;
    const int c0 = (blockIdx.x >> 4) * 64;
    const int tid = threadIdx.x;
    const float* xb = x + (size_t)b * NN * CT;
#pragma unroll
    for (int i = 0; i < 4; ++i) {
        int f = i * 256 + tid;
        int mr = f >> 4, c4 = (f & 15) << 2;
        float4 v = *(const float4*)(xb + (size_t)(m0 + mr) * CT + c0 + c4);
        ushort4 u;
        u.x = f2bf(v.x); u.y = f2bf(v.y); u.z = f2bf(v.z); u.w = f2bf(v.w);
        *(ushort4*)&tile[mr][c4] = u;
    }
    __syncthreads();
    ushort* outp = Xt + (size_t)b * CT * NN;
#pragma unroll
    for (int i = 0; i < 4; ++i) {
        int f = i * 256 + tid;
        int n = f >> 4, m4 = (f & 15) << 2;
        int ctlin = c0 + n;                     // = c*36 + t
        int c = ctlin / 36, t = ctlin - 36 * c;
        int ctp = t * 16 + c;                   // t-major permuted row
        ushort4 u;
        u.x = tile[m4 + 0][n]; u.y = tile[m4 + 1][n];
        u.z = tile[m4 + 2][n]; u.w = tile[m4 + 3][n];
        *(ushort4*)(outp + (size_t)ctp * NN + m0 + m4) = u;
    }
}

// -------- gemm1: rhs2[b][n][t][k*16+c] = sum_m At[n][m] * Xt[b][ct'][m] --------
// Tile BM=128(n) x BN=192(ct') x BK=64. Epilogue LDS-staged -> 32B segments.
__global__ __launch_bounds__(256) void gemm1(const ushort* __restrict__ At,
                                             const ushort* __restrict__ Xt,
                                             ushort* __restrict__ rhs2,
                                             int k0, int n_base, int rows) {
    __shared__ ushort smem[128 * 200];            // 51.2 KB; lA/lB in first 40 KB
    ushort* lA = smem;                            // 128*64
    ushort* lB = smem + 128 * 64;                 // 192*64
    const int tid = threadIdx.x;
    const int gl = k0 * 16 + blockIdx.y;
    const int b = gl & 15, k = gl >> 4;
    const int nt = blockIdx.x / 3, ctt = blockIdx.x % 3;
    const int nloc0 = nt * 128;
    const int ct0 = ctt * 192;
    const ushort* Ab = At + (size_t)blockIdx.y * rows * NN + (size_t)nloc0 * NN;
    const ushort* Bb = Xt + (size_t)b * CT * NN + (size_t)ct0 * NN;
    const int w = tid >> 6, lane = tid & 63;
    const int wr = w >> 1, wc = w & 1;
    const int lrow = lane & 15, quad = lane >> 4;
    f32x4 acc[4][6] = {};

    for (int kt = 0; kt < 16; ++kt) {
        const int mk = kt * 64;
#pragma unroll
        for (int i = 0; i < 4; ++i) {
            int f = i * 256 + tid;
            int row = f >> 3, kk = (f & 7) << 3;
            __builtin_amdgcn_global_load_lds(
                (const __attribute__((address_space(1))) void*)(Ab + (size_t)row * NN + mk + kk),
                (__attribute__((address_space(3))) void*)(&lA[f * 8]), 16, 0, 0);
        }
#pragma unroll
        for (int i = 0; i < 6; ++i) {
            int f = i * 256 + tid;
            int row = f >> 3, kk = (f & 7) << 3;
            __builtin_amdgcn_global_load_lds(
                (const __attribute__((address_space(1))) void*)(Bb + (size_t)row * NN + mk + kk),
                (__attribute__((address_space(3))) void*)(&lB[f * 8]), 16, 0, 0);
        }
        __syncthreads();
#pragma unroll
        for (int kk0 = 0; kk0 < 64; kk0 += 32) {
            bf16x8 af[4], bfr[6];
#pragma unroll
            for (int mi = 0; mi < 4; ++mi)
                af[mi] = *(const bf16x8*)&lA[(wr * 64 + mi * 16 + lrow) * 64 + kk0 + quad * 8];
#pragma unroll
            for (int ni = 0; ni < 6; ++ni)
                bfr[ni] = *(const bf16x8*)&lB[(wc * 96 + ni * 16 + lrow) * 64 + kk0 + quad * 8];
#pragma unroll
            for (int mi = 0; mi < 4; ++mi)
#pragma unroll
                for (int ni = 0; ni < 6; ++ni)
                    acc[mi][ni] = __builtin_amdgcn_mfma_f32_16x16x32_bf16(
                        af[mi], bfr[ni], acc[mi][ni], 0, 0, 0);
        }
        __syncthreads();
    }

    // stage C (bf16) into LDS: row stride 200 breaks bank alignment
#pragma unroll
    for (int mi = 0; mi < 4; ++mi)
#pragma unroll
        for (int ni = 0; ni < 6; ++ni)
#pragma unroll
            for (int r = 0; r < 4; ++r)
                smem[(wr * 64 + mi * 16 + quad * 4 + r) * 200 + wc * 96 + ni * 16 + lrow] =
                    f2bf(acc[mi][ni][r]);
    __syncthreads();

    // cooperative store: 128 n x 12 t x 32B (16 c) segments into rhs2[b][n][t][48]
    for (int f = tid; f < 1536; f += 256) {
        int n = f / 12, tl = f - 12 * (f / 12);
        int t = ctt * 12 + tl;
        uint4 v0 = *(const uint4*)&smem[n * 200 + tl * 16];
        uint4 v1 = *(const uint4*)&smem[n * 200 + tl * 16 + 8];
        size_t g = (((size_t)b * NN + n_base + nloc0 + n) * 36 + t) * 48 + k * 16;
        *(uint4*)(rhs2 + g) = v0;
        *(uint4*)(rhs2 + g + 8) = v1;
    }
}

// -------- apply_mfma2: out[b,n,o,t] = relu(sum_kc rhs2[b,n,t,kc] * theta[kc,o]) --------
// 16 bn per block (4 per wave, sequential). Stores LDS-staged for 1KB bursts.
__global__ __launch_bounds__(256) void apply_mfma2(const ushort* __restrict__ rhs2,
                                                   const float* __restrict__ theta,
                                                   float* __restrict__ out) {
    __shared__ ushort thT[64 * 72];       // [o][kc], kc in [48,64) zeroed
    __shared__ float ostage[4][64 * 36];  // per-wave staging, 9216 B each
    const int tid = threadIdx.x;
    for (int f = tid; f < 64 * 64; f += 256) {
        int o = f >> 6, kc = f & 63;
        thT[o * 72 + kc] = f2bf((kc < 48) ? theta[kc * 64 + o] : 0.f);
    }
    __syncthreads();
    const int w = tid >> 6, lane = tid & 63;
    const int lrow = lane & 15, quad = lane >> 4;

    bf16x8 a[4][2];
#pragma unroll
    for (int mi = 0; mi < 4; ++mi)
#pragma unroll
        for (int kc = 0; kc < 2; ++kc)
            a[mi][kc] = *(const bf16x8*)&thT[(mi * 16 + lrow) * 72 + kc * 32 + quad * 8];

    float* ost = &ostage[w][0];
    for (int j = 0; j < 4; ++j) {
        const int bn = blockIdx.x * 16 + w * 4 + j;
        const ushort* rrow = rhs2 + (size_t)bn * (36 * 48);
        f32x4 acc[4][3] = {};
#pragma unroll
        for (int ni = 0; ni < 3; ++ni)
#pragma unroll
            for (int kc = 0; kc < 2; ++kc) {
                // t-col >= 36 and kc-pad read in-bounds garbage (rhs2 is first in
                // ws, Xt follows): masked by zero theta rows / t<36 staging guard.
                bf16x8 bf = *(const bf16x8*)(rrow + (ni * 16 + lrow) * 48 + kc * 32 + quad * 8);
#pragma unroll
                for (int mi = 0; mi < 4; ++mi)
                    acc[mi][ni] = __builtin_amdgcn_mfma_f32_16x16x32_bf16(
                        a[mi][kc], bf, acc[mi][ni], 0, 0, 0);
            }
#pragma unroll
        for (int mi = 0; mi < 4; ++mi)
#pragma unroll
            for (int ni = 0; ni < 3; ++ni)
#pragma unroll
                for (int r = 0; r < 4; ++r) {
                    int t = ni * 16 + lrow;
                    if (t < 36)
                        ost[(mi * 16 + quad * 4 + r) * 36 + t] = fmaxf(acc[mi][ni][r], 0.f);
                }
        // wave-local LDS write->read across lanes: drain lgkm explicitly
        asm volatile("s_waitcnt lgkmcnt(0)" ::: "memory");
        float* ob = out + (size_t)bn * (COUT * TT);
#pragma unroll
        for (int q = 0; q < 9; ++q) {
            int f = q * 64 + lane;            // 576 float4 per row
            *(float4*)&ob[f * 4] = *(const float4*)&ost[f * 4];
        }
    }
}

// -------- naive fallback: zero workspace, fully fused --------
__global__ __launch_bounds__(256) void naive_fused(const float* __restrict__ x,
                                                   const float* __restrict__ sat,
                                                   const float* __restrict__ cheb,
                                                   const float* __restrict__ theta,
                                                   float* __restrict__ out) {
    __shared__ float wgt[3][1024];
    __shared__ float rs[3][576];
    const int tid = threadIdx.x;
    const int n = blockIdx.x, b = blockIdx.y;
    for (int f = tid; f < 3 * 1024; f += 256) {
        int k = f >> 10, m = f & 1023;
        wgt[k][m] = cheb[(size_t)k * NN * NN + (size_t)m * NN + n] *
                    sat[(size_t)b * NN * NN + (size_t)m * NN + n];
    }
    __syncthreads();
    float a0[3] = {}, a1[3] = {}, a2[3] = {};
    const float* xb = x + (size_t)b * NN * CT;
    for (int m = 0; m < 1024; ++m) {
        const float* xr = xb + (size_t)m * CT;
        float x0 = xr[tid];
        float x1 = xr[256 + tid];
        float x2 = (tid < 64) ? xr[512 + tid] : 0.f;
#pragma unroll
        for (int k = 0; k < 3; ++k) {
            float wm = wgt[k][m];
            a0[k] += wm * x0; a1[k] += wm * x1; a2[k] += wm * x2;
        }
    }
#pragma unroll
    for (int k = 0; k < 3; ++k) {
        rs[k][tid] = a0[k];
        rs[k][256 + tid] = a1[k];
        if (tid < 64) rs[k][512 + tid] = a2[k];
    }
    __syncthreads();
    const int o = tid >> 2, tg = tid & 3;
    float oa[9] = {};
    for (int kc = 0; kc < 48; ++kc) {
        int k = kc >> 4, c = kc & 15;
        float th = theta[kc * 64 + o];
        const float* rp = &rs[k][c * TT + tg * 9];
#pragma unroll
        for (int j = 0; j < 9; ++j) oa[j] += th * rp[j];
    }
    float* ob = out + ((size_t)b * NN + n) * (COUT * TT);
#pragma unroll
    for (int j = 0; j < 9; ++j)
        ob[o * TT + tg * 9 + j] = fmaxf(oa[j], 0.f);
}

extern "C" void kernel_launch(void* const* d_in, const int* in_sizes, int n_in,
                              void* d_out, int out_size, void* d_ws, size_t ws_size,
                              hipStream_t stream) {
    const float* x     = (const float*)d_in[0];   // [B,N,CIN,T]
    const float* sat   = (const float*)d_in[1];   // [B,N,N]
    const float* cheb  = (const float*)d_in[2];   // [K,N,N]
    const float* theta = (const float*)d_in[3];   // [K,CIN,COUT]
    float* out = (float*)d_out;

    const size_t RHS2 = (size_t)NB * NN * 36 * 48;   // 28.3M ushorts (56.6 MB)
    const size_t XT   = (size_t)NB * CT * NN;        //  9.4M (18.9 MB)
    const size_t ATF  = (size_t)KB * NN * NN;        // 50.3M (100.7 MB) full At
    const size_t ATNS = (size_t)KB * 512 * NN;       // 25.2M (50.3 MB) n-half chunk
    const size_t needA     = (RHS2 + XT + ATF) * 2;  // 176,160,768 B
    const size_t needSplit = (RHS2 + XT + ATNS) * 2; // 125,829,120 B

    // layout: rhs2 FIRST (apply's bounded over-reads land in Xt), then Xt, At
    ushort* rhs2 = (ushort*)d_ws;
    ushort* Xt   = rhs2 + RHS2;
    ushort* At   = Xt + XT;

    if (ws_size >= needA) {
        prep_x<<<dim3(144, NB), 256, 0, stream>>>(x, Xt);
        prep_a<<<dim3(256, KB), 256, 0, stream>>>(cheb, sat, At, 0, 0, 1024);
        gemm1<<<dim3(24, KB), 256, 0, stream>>>(At, Xt, rhs2, 0, 0, 1024);
        apply_mfma2<<<dim3(NB * NN / 16), 256, 0, stream>>>(rhs2, theta, out);
    } else if (ws_size >= needSplit) {
        prep_x<<<dim3(144, NB), 256, 0, stream>>>(x, Xt);
        for (int half = 0; half < 2; ++half) {
            int nb = half * 512;
            prep_a<<<dim3(128, KB), 256, 0, stream>>>(cheb, sat, At, 0, nb, 512);
            gemm1<<<dim3(12, KB), 256, 0, stream>>>(At, Xt, rhs2, 0, nb, 512);
        }
        apply_mfma2<<<dim3(NB * NN / 16), 256, 0, stream>>>(rhs2, theta, out);
    } else {
        naive_fused<<<dim3(NN, NB), 256, 0, stream>>>(x, sat, cheb, theta, out);
    }
}

// Round 5
// 419.052 us; speedup vs baseline: 1.1368x; 1.0623x over previous
//
#include <hip/hip_runtime.h>
#include <hip/hip_bf16.h>

// Problem constants
#define NB 16      // batch
#define NN 1024    // nodes
#define CIN 16
#define TT 36
#define KK 3
#define COUT 64
#define CT 576     // CIN*TT
#define KB 48      // KK*NB

typedef __attribute__((ext_vector_type(8))) short bf16x8;
typedef __attribute__((ext_vector_type(4))) float f32x4;

__device__ __forceinline__ unsigned short f2bf(float f) {
    union { float f; unsigned int u; } v; v.f = f;
    unsigned int r = v.u + 0x7FFF + ((v.u >> 16) & 1);
    return (unsigned short)(r >> 16);
}

// -------- prep_a: At[l_loc][n - n_base][m] = bf16(cheb[k][m][n] * SAt[b][m][n]) --------
__global__ __launch_bounds__(256) void prep_a(const float* __restrict__ cheb,
                                              const float* __restrict__ sat,
                                              ushort* __restrict__ At,
                                              int k0, int n_base, int rows) {
    __shared__ ushort tile[64][68];
    const int ntiles = rows >> 6;
    const int gl = k0 * 16 + blockIdx.y;
    const int k = gl >> 4, b = gl & 15;
    const int n0 = n_base + (blockIdx.x % ntiles) * 64;
    const int m0 = (blockIdx.x / ntiles) * 64;
    const int tid = threadIdx.x;
    const float* cb = cheb + (size_t)k * NN * NN;
    const float* sa = sat + (size_t)b * NN * NN;
#pragma unroll
    for (int i = 0; i < 4; ++i) {
        int f = i * 256 + tid;
        int mr = f >> 4, c4 = (f & 15) << 2;
        size_t g = (size_t)(m0 + mr) * NN + n0 + c4;
        float4 cv = *(const float4*)(cb + g);
        float4 sv = *(const float4*)(sa + g);
        ushort4 u;
        u.x = f2bf(cv.x * sv.x); u.y = f2bf(cv.y * sv.y);
        u.z = f2bf(cv.z * sv.z); u.w = f2bf(cv.w * sv.w);
        *(ushort4*)&tile[mr][c4] = u;
    }
    __syncthreads();
    ushort* outp = At + (size_t)blockIdx.y * rows * NN;
#pragma unroll
    for (int i = 0; i < 4; ++i) {
        int f = i * 256 + tid;
        int n = f >> 4, m4 = (f & 15) << 2;
        ushort4 u;
        u.x = tile[m4 + 0][n]; u.y = tile[m4 + 1][n];
        u.z = tile[m4 + 2][n]; u.w = tile[m4 + 3][n];
        *(ushort4*)(outp + (size_t)(n0 - n_base + n) * NN + m0 + m4) = u;
    }
}

// -------- prep_x: Xt[b][ct'][m] = bf16(x[b][m][c][t]), ct' = t*16 + c --------
__global__ __launch_bounds__(256) void prep_x(const float* __restrict__ x,
                                              ushort* __restrict__ Xt) {
    __shared__ ushort tile[64][68];
    const int b = blockIdx.y;
    const int m0 = (blockIdx.x & 15) * 64;
    const int c0 = (blockIdx.x >> 4) * 64;
    const int tid = threadIdx.x;
    const float* xb = x + (size_t)b * NN * CT;
#pragma unroll
    for (int i = 0; i < 4; ++i) {
        int f = i * 256 + tid;
        int mr = f >> 4, c4 = (f & 15) << 2;
        float4 v = *(const float4*)(xb + (size_t)(m0 + mr) * CT + c0 + c4);
        ushort4 u;
        u.x = f2bf(v.x); u.y = f2bf(v.y); u.z = f2bf(v.z); u.w = f2bf(v.w);
        *(ushort4*)&tile[mr][c4] = u;
    }
    __syncthreads();
    ushort* outp = Xt + (size_t)b * CT * NN;
#pragma unroll
    for (int i = 0; i < 4; ++i) {
        int f = i * 256 + tid;
        int n = f >> 4, m4 = (f & 15) << 2;
        int ctlin = c0 + n;                     // = c*36 + t
        int c = ctlin / 36, t = ctlin - 36 * c;
        int ctp = t * 16 + c;                   // t-major permuted row
        ushort4 u;
        u.x = tile[m4 + 0][n]; u.y = tile[m4 + 1][n];
        u.z = tile[m4 + 2][n]; u.w = tile[m4 + 3][n];
        *(ushort4*)(outp + (size_t)ctp * NN + m0 + m4) = u;
    }
}

// -------- gemm1: rhs2[b][n][t][k*16+c] = sum_m At[n][m] * Xt[b][ct'][m] --------
// Tile BM=128(n) x BN=192(ct') x BK=64.
// XCD swizzle: flat id = x + 24*y, 24y % 8 == 0 -> XCD = x % 8 (round-robin model).
//   nt = x%8, ctt = x/8: the 3 blocks sharing an A-slice (same nt, ctt=0,1,2)
//   sit at x, x+8, x+16 -> same XCD -> A-slice served from that XCD's L2.
//   y: b = y/3, k = y%3 -> 3 consecutive y share Xt[b] (B chunks L2/L3-hot).
__global__ __launch_bounds__(256) void gemm1(const ushort* __restrict__ At,
                                             const ushort* __restrict__ Xt,
                                             ushort* __restrict__ rhs2,
                                             int nsplit, int n_base, int rows) {
    __shared__ ushort smem[128 * 200];            // 51.2 KB; lA/lB in first 40 KB
    ushort* lA = smem;                            // 128*64
    ushort* lB = smem + 128 * 64;                 // 192*64
    const int tid = threadIdx.x;
    const int y = blockIdx.y;
    const int b = y / 3, k = y - 3 * b;           // Xt-sharing trios adjacent
    const int l = k * 16 + b;                     // At chunk index (layout unchanged)
    const int ntiles = rows >> 7;                 // 128-row tiles in this chunk
    const int nt = blockIdx.x % ntiles;           // XCD-aligned A-slice id
    const int ctt = blockIdx.x / ntiles;          // 3 ct-tiles -> same XCD
    const int nloc0 = nt * 128;
    const int ct0 = ctt * 192;
    const ushort* Ab = At + ((size_t)l * (nsplit ? rows : NN) + nloc0) * NN;
    const ushort* Bb = Xt + (size_t)b * CT * NN + (size_t)ct0 * NN;
    const int w = tid >> 6, lane = tid & 63;
    const int wr = w >> 1, wc = w & 1;
    const int lrow = lane & 15, quad = lane >> 4;
    f32x4 acc[4][6] = {};

    for (int kt = 0; kt < 16; ++kt) {
        const int mk = kt * 64;
#pragma unroll
        for (int i = 0; i < 4; ++i) {
            int f = i * 256 + tid;
            int row = f >> 3, kk = (f & 7) << 3;
            __builtin_amdgcn_global_load_lds(
                (const __attribute__((address_space(1))) void*)(Ab + (size_t)row * NN + mk + kk),
                (__attribute__((address_space(3))) void*)(&lA[f * 8]), 16, 0, 0);
        }
#pragma unroll
        for (int i = 0; i < 6; ++i) {
            int f = i * 256 + tid;
            int row = f >> 3, kk = (f & 7) << 3;
            __builtin_amdgcn_global_load_lds(
                (const __attribute__((address_space(1))) void*)(Bb + (size_t)row * NN + mk + kk),
                (__attribute__((address_space(3))) void*)(&lB[f * 8]), 16, 0, 0);
        }
        __syncthreads();
#pragma unroll
        for (int kk0 = 0; kk0 < 64; kk0 += 32) {
            bf16x8 af[4], bfr[6];
#pragma unroll
            for (int mi = 0; mi < 4; ++mi)
                af[mi] = *(const bf16x8*)&lA[(wr * 64 + mi * 16 + lrow) * 64 + kk0 + quad * 8];
#pragma unroll
            for (int ni = 0; ni < 6; ++ni)
                bfr[ni] = *(const bf16x8*)&lB[(wc * 96 + ni * 16 + lrow) * 64 + kk0 + quad * 8];
#pragma unroll
            for (int mi = 0; mi < 4; ++mi)
#pragma unroll
                for (int ni = 0; ni < 6; ++ni)
                    acc[mi][ni] = __builtin_amdgcn_mfma_f32_16x16x32_bf16(
                        af[mi], bfr[ni], acc[mi][ni], 0, 0, 0);
        }
        __syncthreads();
    }

    // stage C (bf16) into LDS: row stride 200 breaks bank alignment
#pragma unroll
    for (int mi = 0; mi < 4; ++mi)
#pragma unroll
        for (int ni = 0; ni < 6; ++ni)
#pragma unroll
            for (int r = 0; r < 4; ++r)
                smem[(wr * 64 + mi * 16 + quad * 4 + r) * 200 + wc * 96 + ni * 16 + lrow] =
                    f2bf(acc[mi][ni][r]);
    __syncthreads();

    // cooperative store: 128 n x 12 t x 32B (16 c) segments into rhs2[b][n][t][48]
    for (int f = tid; f < 1536; f += 256) {
        int n = f / 12, tl = f - 12 * (f / 12);
        int t = ctt * 12 + tl;
        uint4 v0 = *(const uint4*)&smem[n * 200 + tl * 16];
        uint4 v1 = *(const uint4*)&smem[n * 200 + tl * 16 + 8];
        size_t g = (((size_t)b * NN + n_base + nloc0 + n) * 36 + t) * 48 + k * 16;
        *(uint4*)(rhs2 + g) = v0;
        *(uint4*)(rhs2 + g + 8) = v1;
    }
}

// -------- apply_mfma2: out[b,n,o,t] = relu(sum_kc rhs2[b,n,t,kc] * theta[kc,o]) --------
// 16 bn per block (4 per wave, sequential). Stores LDS-staged for 1KB bursts.
__global__ __launch_bounds__(256) void apply_mfma2(const ushort* __restrict__ rhs2,
                                                   const float* __restrict__ theta,
                                                   float* __restrict__ out) {
    __shared__ ushort thT[64 * 72];       // [o][kc], kc in [48,64) zeroed
    __shared__ float ostage[4][64 * 36];  // per-wave staging, 9216 B each
    const int tid = threadIdx.x;
    for (int f = tid; f < 64 * 64; f += 256) {
        int o = f >> 6, kc = f & 63;
        thT[o * 72 + kc] = f2bf((kc < 48) ? theta[kc * 64 + o] : 0.f);
    }
    __syncthreads();
    const int w = tid >> 6, lane = tid & 63;
    const int lrow = lane & 15, quad = lane >> 4;

    bf16x8 a[4][2];
#pragma unroll
    for (int mi = 0; mi < 4; ++mi)
#pragma unroll
        for (int kc = 0; kc < 2; ++kc)
            a[mi][kc] = *(const bf16x8*)&thT[(mi * 16 + lrow) * 72 + kc * 32 + quad * 8];

    float* ost = &ostage[w][0];
    for (int j = 0; j < 4; ++j) {
        const int bn = blockIdx.x * 16 + w * 4 + j;
        const ushort* rrow = rhs2 + (size_t)bn * (36 * 48);
        f32x4 acc[4][3] = {};
#pragma unroll
        for (int ni = 0; ni < 3; ++ni)
#pragma unroll
            for (int kc = 0; kc < 2; ++kc) {
                // t-col >= 36 and kc-pad read in-bounds garbage (rhs2 is first in
                // ws, Xt follows): masked by zero theta rows / t<36 staging guard.
                bf16x8 bf = *(const bf16x8*)(rrow + (ni * 16 + lrow) * 48 + kc * 32 + quad * 8);
#pragma unroll
                for (int mi = 0; mi < 4; ++mi)
                    acc[mi][ni] = __builtin_amdgcn_mfma_f32_16x16x32_bf16(
                        a[mi][kc], bf, acc[mi][ni], 0, 0, 0);
            }
#pragma unroll
        for (int mi = 0; mi < 4; ++mi)
#pragma unroll
            for (int ni = 0; ni < 3; ++ni)
#pragma unroll
                for (int r = 0; r < 4; ++r) {
                    int t = ni * 16 + lrow;
                    if (t < 36)
                        ost[(mi * 16 + quad * 4 + r) * 36 + t] = fmaxf(acc[mi][ni][r], 0.f);
                }
        // wave-local LDS write->read across lanes: drain lgkm explicitly
        asm volatile("s_waitcnt lgkmcnt(0)" ::: "memory");
        float* ob = out + (size_t)bn * (COUT * TT);
#pragma unroll
        for (int q = 0; q < 9; ++q) {
            int f = q * 64 + lane;            // 576 float4 per row
            *(float4*)&ob[f * 4] = *(const float4*)&ost[f * 4];
        }
    }
}

// -------- naive fallback: zero workspace, fully fused --------
__global__ __launch_bounds__(256) void naive_fused(const float* __restrict__ x,
                                                   const float* __restrict__ sat,
                                                   const float* __restrict__ cheb,
                                                   const float* __restrict__ theta,
                                                   float* __restrict__ out) {
    __shared__ float wgt[3][1024];
    __shared__ float rs[3][576];
    const int tid = threadIdx.x;
    const int n = blockIdx.x, b = blockIdx.y;
    for (int f = tid; f < 3 * 1024; f += 256) {
        int k = f >> 10, m = f & 1023;
        wgt[k][m] = cheb[(size_t)k * NN * NN + (size_t)m * NN + n] *
                    sat[(size_t)b * NN * NN + (size_t)m * NN + n];
    }
    __syncthreads();
    float a0[3] = {}, a1[3] = {}, a2[3] = {};
    const float* xb = x + (size_t)b * NN * CT;
    for (int m = 0; m < 1024; ++m) {
        const float* xr = xb + (size_t)m * CT;
        float x0 = xr[tid];
        float x1 = xr[256 + tid];
        float x2 = (tid < 64) ? xr[512 + tid] : 0.f;
#pragma unroll
        for (int k = 0; k < 3; ++k) {
            float wm = wgt[k][m];
            a0[k] += wm * x0; a1[k] += wm * x1; a2[k] += wm * x2;
        }
    }
#pragma unroll
    for (int k = 0; k < 3; ++k) {
        rs[k][tid] = a0[k];
        rs[k][256 + tid] = a1[k];
        if (tid < 64) rs[k][512 + tid] = a2[k];
    }
    __syncthreads();
    const int o = tid >> 2, tg = tid & 3;
    float oa[9] = {};
    for (int kc = 0; kc < 48; ++kc) {
        int k = kc >> 4, c = kc & 15;
        float th = theta[kc * 64 + o];
        const float* rp = &rs[k][c * TT + tg * 9];
#pragma unroll
        for (int j = 0; j < 9; ++j) oa[j] += th * rp[j];
    }
    float* ob = out + ((size_t)b * NN + n) * (COUT * TT);
#pragma unroll
    for (int j = 0; j < 9; ++j)
        ob[o * TT + tg * 9 + j] = fmaxf(oa[j], 0.f);
}

extern "C" void kernel_launch(void* const* d_in, const int* in_sizes, int n_in,
                              void* d_out, int out_size, void* d_ws, size_t ws_size,
                              hipStream_t stream) {
    const float* x     = (const float*)d_in[0];   // [B,N,CIN,T]
    const float* sat   = (const float*)d_in[1];   // [B,N,N]
    const float* cheb  = (const float*)d_in[2];   // [K,N,N]
    const float* theta = (const float*)d_in[3];   // [K,CIN,COUT]
    float* out = (float*)d_out;

    const size_t RHS2 = (size_t)NB * NN * 36 * 48;   // 28.3M ushorts (56.6 MB)
    const size_t XT   = (size_t)NB * CT * NN;        //  9.4M (18.9 MB)
    const size_t ATF  = (size_t)KB * NN * NN;        // 50.3M (100.7 MB) full At
    const size_t ATNS = (size_t)KB * 512 * NN;       // 25.2M (50.3 MB) n-half chunk
    const size_t needA     = (RHS2 + XT + ATF) * 2;  // 176,160,768 B
    const size_t needSplit = (RHS2 + XT + ATNS) * 2; // 125,829,120 B

    // layout: rhs2 FIRST (apply's bounded over-reads land in Xt), then Xt, At
    ushort* rhs2 = (ushort*)d_ws;
    ushort* Xt   = rhs2 + RHS2;
    ushort* At   = Xt + XT;

    if (ws_size >= needA) {
        prep_x<<<dim3(144, NB), 256, 0, stream>>>(x, Xt);
        prep_a<<<dim3(256, KB), 256, 0, stream>>>(cheb, sat, At, 0, 0, 1024);
        gemm1<<<dim3(24, KB), 256, 0, stream>>>(At, Xt, rhs2, 0, 0, 1024);
        apply_mfma2<<<dim3(NB * NN / 16), 256, 0, stream>>>(rhs2, theta, out);
    } else if (ws_size >= needSplit) {
        prep_x<<<dim3(144, NB), 256, 0, stream>>>(x, Xt);
        for (int half = 0; half < 2; ++half) {
            int nb = half * 512;
            prep_a<<<dim3(128, KB), 256, 0, stream>>>(cheb, sat, At, 0, nb, 512);
            gemm1<<<dim3(12, KB), 256, 0, stream>>>(At, Xt, rhs2, 1, nb, 512);
        }
        apply_mfma2<<<dim3(NB * NN / 16), 256, 0, stream>>>(rhs2, theta, out);
    } else {
        naive_fused<<<dim3(NN, NB), 256, 0, stream>>>(x, sat, cheb, theta, out);
    }
}